// Round 1
// baseline (153.176 us; speedup 1.0000x reference)
//
#include <hip/hip_runtime.h>

// TRecPolicy: per-row fused {7x up-GRU(2->4), MLP 8->4->4, 7x down-GRU(4->4), 7 output dots}
// One thread per row; fully unrolled; weights via uniform scalar loads.

__device__ __forceinline__ float fsig(float x) {
    // sigmoid(x) = 1/(1+exp(-x))
    float e = __expf(-x);
    return __builtin_amdgcn_rcpf(1.0f + e);
}
__device__ __forceinline__ float ftanh(float x) {
    // tanh(x) = 2/(1+exp(-2x)) - 1
    float e = __expf(-2.0f * x);
    return fmaf(2.0f, __builtin_amdgcn_rcpf(1.0f + e), -1.0f);
}

__global__ void __launch_bounds__(256) trec_kernel(
    const float* __restrict__ x,
    const float* __restrict__ w_ih_up, const float* __restrict__ w_hh_up,
    const float* __restrict__ b_ih_up, const float* __restrict__ b_hh_up,
    const float* __restrict__ w1, const float* __restrict__ b1,
    const float* __restrict__ w2, const float* __restrict__ b2,
    const float* __restrict__ w_ih_dn, const float* __restrict__ w_hh_dn,
    const float* __restrict__ b_ih_dn, const float* __restrict__ b_hh_dn,
    const float* __restrict__ w_out, const float* __restrict__ b_out,
    float* __restrict__ out, int n)
{
    int row = blockIdx.x * blockDim.x + threadIdx.x;
    if (row >= n) return;

    // ---- load the 18-float row as 9x float2 (72B row stride, 8B aligned) ----
    float xv[18];
    {
        const float2* xp = reinterpret_cast<const float2*>(x + (size_t)row * 18u);
        #pragma unroll
        for (int k = 0; k < 9; ++k) {
            float2 v = xp[k];
            xv[2*k]   = v.x;
            xv[2*k+1] = v.y;
        }
    }
    // obs = xv[0..3], j = xv[4..10], jd = xv[11..17]

    float h[4] = {0.f, 0.f, 0.f, 0.f};
    float hup[7][4];

    // ---- up GRU: i = 6..0, xi = [j[i], jd[i]] ----
    #pragma unroll
    for (int s = 0; s < 7; ++s) {
        const int i = 6 - s;
        const float x0 = xv[4 + i];
        const float x1 = xv[11 + i];
        float r[4], z[4], nn[4];
        #pragma unroll
        for (int d = 0; d < 4; ++d) {                 // r gate (k = d)
            float gi = fmaf(x1, w_ih_up[2*d+1], fmaf(x0, w_ih_up[2*d], b_ih_up[d]));
            float gh = b_hh_up[d];
            #pragma unroll
            for (int e = 0; e < 4; ++e) gh = fmaf(h[e], w_hh_up[4*d+e], gh);
            r[d] = fsig(gi + gh);
        }
        #pragma unroll
        for (int d = 0; d < 4; ++d) {                 // z gate (k = 4+d)
            const int k = 4 + d;
            float gi = fmaf(x1, w_ih_up[2*k+1], fmaf(x0, w_ih_up[2*k], b_ih_up[k]));
            float gh = b_hh_up[k];
            #pragma unroll
            for (int e = 0; e < 4; ++e) gh = fmaf(h[e], w_hh_up[4*k+e], gh);
            z[d] = fsig(gi + gh);
        }
        #pragma unroll
        for (int d = 0; d < 4; ++d) {                 // n gate (k = 8+d)
            const int k = 8 + d;
            float gi = fmaf(x1, w_ih_up[2*k+1], fmaf(x0, w_ih_up[2*k], b_ih_up[k]));
            float gh = b_hh_up[k];
            #pragma unroll
            for (int e = 0; e < 4; ++e) gh = fmaf(h[e], w_hh_up[4*k+e], gh);
            nn[d] = ftanh(fmaf(r[d], gh, gi));
        }
        #pragma unroll
        for (int d = 0; d < 4; ++d) {
            float hn = fmaf(z[d], h[d] - nn[d], nn[d]);  // (1-z)*n + z*h
            h[d] = hn;
            hup[s][d] = hn;
        }
    }

    // ---- MLP: tanh([obs,h] @ w1.T + b1) -> tanh(@ w2.T + b2) ----
    {
        float in8[8];
        #pragma unroll
        for (int d = 0; d < 4; ++d) in8[d] = xv[d];
        #pragma unroll
        for (int d = 0; d < 4; ++d) in8[4+d] = h[d];
        float t1[4];
        #pragma unroll
        for (int k = 0; k < 4; ++k) {
            float a = b1[k];
            #pragma unroll
            for (int d = 0; d < 8; ++d) a = fmaf(in8[d], w1[8*k+d], a);
            t1[k] = ftanh(a);
        }
        #pragma unroll
        for (int k = 0; k < 4; ++k) {
            float a = b2[k];
            #pragma unroll
            for (int d = 0; d < 4; ++d) a = fmaf(t1[d], w2[4*k+d], a);
            h[k] = ftanh(a);
        }
    }

    // ---- down GRU: i = 0..6, xi = hup[i]; act = [h, j[i]] @ w_out.T + b_out ----
    float acts[7];
    #pragma unroll
    for (int i = 0; i < 7; ++i) {
        float r[4], z[4], nn[4];
        #pragma unroll
        for (int d = 0; d < 4; ++d) {                 // r gate
            float gi = b_ih_dn[d];
            float gh = b_hh_dn[d];
            #pragma unroll
            for (int e = 0; e < 4; ++e) {
                gi = fmaf(hup[i][e], w_ih_dn[4*d+e], gi);
                gh = fmaf(h[e],      w_hh_dn[4*d+e], gh);
            }
            r[d] = fsig(gi + gh);
        }
        #pragma unroll
        for (int d = 0; d < 4; ++d) {                 // z gate
            const int k = 4 + d;
            float gi = b_ih_dn[k];
            float gh = b_hh_dn[k];
            #pragma unroll
            for (int e = 0; e < 4; ++e) {
                gi = fmaf(hup[i][e], w_ih_dn[4*k+e], gi);
                gh = fmaf(h[e],      w_hh_dn[4*k+e], gh);
            }
            z[d] = fsig(gi + gh);
        }
        #pragma unroll
        for (int d = 0; d < 4; ++d) {                 // n gate
            const int k = 8 + d;
            float gi = b_ih_dn[k];
            float gh = b_hh_dn[k];
            #pragma unroll
            for (int e = 0; e < 4; ++e) {
                gi = fmaf(hup[i][e], w_ih_dn[4*k+e], gi);
                gh = fmaf(h[e],      w_hh_dn[4*k+e], gh);
            }
            nn[d] = ftanh(fmaf(r[d], gh, gi));
        }
        #pragma unroll
        for (int d = 0; d < 4; ++d)
            h[d] = fmaf(z[d], h[d] - nn[d], nn[d]);

        float a = b_out[0];
        #pragma unroll
        for (int d = 0; d < 4; ++d) a = fmaf(h[d], w_out[d], a);
        acts[i] = fmaf(xv[4 + i], w_out[4], a);
    }

    // ---- store (2M x 7, row-major) ----
    float* op = out + (size_t)row * 7u;
    #pragma unroll
    for (int i = 0; i < 7; ++i) op[i] = acts[i];
}

extern "C" void kernel_launch(void* const* d_in, const int* in_sizes, int n_in,
                              void* d_out, int out_size, void* d_ws, size_t ws_size,
                              hipStream_t stream)
{
    const float* x       = (const float*)d_in[0];
    const float* w_ih_up = (const float*)d_in[1];
    const float* w_hh_up = (const float*)d_in[2];
    const float* b_ih_up = (const float*)d_in[3];
    const float* b_hh_up = (const float*)d_in[4];
    const float* w1      = (const float*)d_in[5];
    const float* b1      = (const float*)d_in[6];
    const float* w2      = (const float*)d_in[7];
    const float* b2      = (const float*)d_in[8];
    const float* w_ih_dn = (const float*)d_in[9];
    const float* w_hh_dn = (const float*)d_in[10];
    const float* b_ih_dn = (const float*)d_in[11];
    const float* b_hh_dn = (const float*)d_in[12];
    const float* w_out   = (const float*)d_in[13];
    const float* b_out   = (const float*)d_in[14];
    float* out = (float*)d_out;

    const int n = in_sizes[0] / 18;
    const int block = 256;
    const int grid = (n + block - 1) / block;

    trec_kernel<<<grid, block, 0, stream>>>(
        x, w_ih_up, w_hh_up, b_ih_up, b_hh_up,
        w1, b1, w2, b2,
        w_ih_dn, w_hh_dn, b_ih_dn, b_hh_dn,
        w_out, b_out, out, n);
}

// Round 2
// 112.699 us; speedup vs baseline: 1.3592x; 1.3592x over previous
//
#include <hip/hip_runtime.h>

// TRecPolicy fused per-row kernel, round 2: packed-FP32 (v_pk_fma_f32) formulation.
// All 4-wide gate math expressed as float2 ext-vectors packed across gate pairs.

typedef float v2f __attribute__((ext_vector_type(2)));

__device__ __forceinline__ v2f mk2(float a, float b) { v2f r; r.x = a; r.y = b; return r; }
__device__ __forceinline__ v2f spl(float s) { return mk2(s, s); }
__device__ __forceinline__ v2f fma2(v2f a, v2f b, v2f c) { return __builtin_elementwise_fma(a, b, c); }

__device__ __forceinline__ float fexp2(float x) {
#if __has_builtin(__builtin_amdgcn_exp2f)
    return __builtin_amdgcn_exp2f(x);          // v_exp_f32 (computes 2^x)
#else
    return __expf(0.6931471805599453f * x);
#endif
}
__device__ __forceinline__ float frcp(float x) { return __builtin_amdgcn_rcpf(x); }

#define LOG2E 1.44269504088896f

// sigmoid on a packed pair: 1/(1+2^(-x*log2e))
__device__ __forceinline__ v2f sig2(v2f g) {
    v2f t = g * spl(-LOG2E);
    v2f e = mk2(fexp2(t.x), fexp2(t.y));
    v2f d = e + spl(1.0f);
    return mk2(frcp(d.x), frcp(d.y));
}
// tanh on a packed pair: 2/(1+2^(-2x*log2e)) - 1
__device__ __forceinline__ v2f tanh2(v2f g) {
    v2f t = g * spl(-2.0f * LOG2E);
    v2f e = mk2(fexp2(t.x), fexp2(t.y));
    v2f d = e + spl(1.0f);
    v2f r = mk2(frcp(d.x), frcp(d.y));
    return fma2(r, spl(2.0f), spl(-1.0f));
}

// acc += W[k..k+1][:] . h   where W is row-major with row stride 4, packed over
// the two output rows (k, k+1). Weight pairs are wave-uniform (SGPR pairs);
// h-element splats map to op_sel broadcasts.
__device__ __forceinline__ v2f dot4(const float* __restrict__ w, int k,
                                    v2f a, v2f b, v2f acc) {
    acc = fma2(spl(a.x), mk2(w[4 * k + 0], w[4 * k + 4]), acc);
    acc = fma2(spl(a.y), mk2(w[4 * k + 1], w[4 * k + 5]), acc);
    acc = fma2(spl(b.x), mk2(w[4 * k + 2], w[4 * k + 6]), acc);
    acc = fma2(spl(b.y), mk2(w[4 * k + 3], w[4 * k + 7]), acc);
    return acc;
}

__global__ void __launch_bounds__(256) trec_kernel(
    const float* __restrict__ x,
    const float* __restrict__ w_ih_up, const float* __restrict__ w_hh_up,
    const float* __restrict__ b_ih_up, const float* __restrict__ b_hh_up,
    const float* __restrict__ w1, const float* __restrict__ b1,
    const float* __restrict__ w2, const float* __restrict__ b2,
    const float* __restrict__ w_ih_dn, const float* __restrict__ w_hh_dn,
    const float* __restrict__ b_ih_dn, const float* __restrict__ b_hh_dn,
    const float* __restrict__ w_out, const float* __restrict__ b_out,
    float* __restrict__ out, int n)
{
    int row = blockIdx.x * blockDim.x + threadIdx.x;
    if (row >= n) return;

    // ---- load 18-float row as 9x float2 ----
    float xv[18];
    {
        const float2* xp = reinterpret_cast<const float2*>(x + (size_t)row * 18u);
        #pragma unroll
        for (int k = 0; k < 9; ++k) {
            float2 v = xp[k];
            xv[2 * k] = v.x;
            xv[2 * k + 1] = v.y;
        }
    }

    // ---- hoisted uniform bias pairs ----
    v2f bsum_up[4], bsum_dn[4];          // r,z gates: b_ih + b_hh pre-summed
    #pragma unroll
    for (int p = 0; p < 4; ++p) {
        bsum_up[p] = mk2(b_ih_up[2 * p], b_ih_up[2 * p + 1]) + mk2(b_hh_up[2 * p], b_hh_up[2 * p + 1]);
        bsum_dn[p] = mk2(b_ih_dn[2 * p], b_ih_dn[2 * p + 1]) + mk2(b_hh_dn[2 * p], b_hh_dn[2 * p + 1]);
    }
    const v2f bihnA_up = mk2(b_ih_up[8], b_ih_up[9]),  bihnB_up = mk2(b_ih_up[10], b_ih_up[11]);
    const v2f bhhnA_up = mk2(b_hh_up[8], b_hh_up[9]),  bhhnB_up = mk2(b_hh_up[10], b_hh_up[11]);
    const v2f bihnA_dn = mk2(b_ih_dn[8], b_ih_dn[9]),  bihnB_dn = mk2(b_ih_dn[10], b_ih_dn[11]);
    const v2f bhhnA_dn = mk2(b_hh_dn[8], b_hh_dn[9]),  bhhnB_dn = mk2(b_hh_dn[10], b_hh_dn[11]);

    v2f hA = spl(0.f), hB = spl(0.f);
    v2f hupA[7], hupB[7];

    // ---- up GRU: i = 6..0, xi = [j[i], jd[i]] (2-wide input) ----
    #pragma unroll
    for (int s = 0; s < 7; ++s) {
        const int i = 6 - s;
        const v2f X0 = spl(xv[4 + i]);
        const v2f X1 = spl(xv[11 + i]);

        v2f rz[4];
        #pragma unroll
        for (int p = 0; p < 4; ++p) {          // r pairs (k=0,2), z pairs (k=4,6)
            const int k = 2 * p;
            v2f acc = bsum_up[p];
            acc = fma2(X0, mk2(w_ih_up[2 * k], w_ih_up[2 * k + 2]), acc);
            acc = fma2(X1, mk2(w_ih_up[2 * k + 1], w_ih_up[2 * k + 3]), acc);
            acc = dot4(w_hh_up, k, hA, hB, acc);
            rz[p] = acc;
        }
        v2f rA = sig2(rz[0]), rB = sig2(rz[1]);
        v2f zA = sig2(rz[2]), zB = sig2(rz[3]);

        // n gates (k=8..11): gi and gh kept separate for r * gh_n
        v2f giA = bihnA_up, giB = bihnB_up;
        giA = fma2(X0, mk2(w_ih_up[16], w_ih_up[18]), giA);
        giA = fma2(X1, mk2(w_ih_up[17], w_ih_up[19]), giA);
        giB = fma2(X0, mk2(w_ih_up[20], w_ih_up[22]), giB);
        giB = fma2(X1, mk2(w_ih_up[21], w_ih_up[23]), giB);
        v2f ghA = dot4(w_hh_up, 8,  hA, hB, bhhnA_up);
        v2f ghB = dot4(w_hh_up, 10, hA, hB, bhhnB_up);
        v2f nA = tanh2(fma2(rA, ghA, giA));
        v2f nB = tanh2(fma2(rB, ghB, giB));

        hA = fma2(zA, hA - nA, nA);            // (1-z)*n + z*h
        hB = fma2(zB, hB - nB, nB);
        hupA[s] = hA; hupB[s] = hB;
    }

    // ---- MLP: tanh([obs,h] @ w1.T + b1) -> tanh(@ w2.T + b2) ----
    {
        float in8[8] = { xv[0], xv[1], xv[2], xv[3], hA.x, hA.y, hB.x, hB.y };
        v2f t1A, t1B;
        {
            v2f a0 = mk2(b1[0], b1[1]), a1 = mk2(b1[2], b1[3]);
            #pragma unroll
            for (int d = 0; d < 8; ++d) {
                a0 = fma2(spl(in8[d]), mk2(w1[d], w1[8 + d]), a0);
                a1 = fma2(spl(in8[d]), mk2(w1[16 + d], w1[24 + d]), a1);
            }
            t1A = tanh2(a0); t1B = tanh2(a1);
        }
        v2f a0 = dot4(w2, 0, t1A, t1B, mk2(b2[0], b2[1]));
        v2f a1 = dot4(w2, 2, t1A, t1B, mk2(b2[2], b2[3]));
        hA = tanh2(a0); hB = tanh2(a1);
    }

    // ---- down GRU: i = 0..6, xi = hup[i]; act = [h, j[i]] @ w_out.T + b_out ----
    const float wo0 = w_out[0], wo1 = w_out[1], wo2 = w_out[2], wo3 = w_out[3], wo4 = w_out[4];
    const float bo = b_out[0];
    float acts[7];
    #pragma unroll
    for (int i = 0; i < 7; ++i) {
        const v2f xiA = hupA[i], xiB = hupB[i];

        v2f rz[4];
        #pragma unroll
        for (int p = 0; p < 4; ++p) {
            const int k = 2 * p;
            v2f acc = bsum_dn[p];
            acc = dot4(w_ih_dn, k, xiA, xiB, acc);
            acc = dot4(w_hh_dn, k, hA, hB, acc);
            rz[p] = acc;
        }
        v2f rA = sig2(rz[0]), rB = sig2(rz[1]);
        v2f zA = sig2(rz[2]), zB = sig2(rz[3]);

        v2f giA = dot4(w_ih_dn, 8,  xiA, xiB, bihnA_dn);
        v2f giB = dot4(w_ih_dn, 10, xiA, xiB, bihnB_dn);
        v2f ghA = dot4(w_hh_dn, 8,  hA, hB, bhhnA_dn);
        v2f ghB = dot4(w_hh_dn, 10, hA, hB, bhhnB_dn);
        v2f nA = tanh2(fma2(rA, ghA, giA));
        v2f nB = tanh2(fma2(rB, ghB, giB));

        hA = fma2(zA, hA - nA, nA);
        hB = fma2(zB, hB - nB, nB);

        v2f t = fma2(hA, mk2(wo0, wo1), mk2(bo, 0.f));
        t = fma2(hB, mk2(wo2, wo3), t);
        acts[i] = fmaf(xv[4 + i], wo4, t.x + t.y);
    }

    // ---- store (n x 7, row-major) ----
    float* op = out + (size_t)row * 7u;
    #pragma unroll
    for (int i = 0; i < 7; ++i) op[i] = acts[i];
}

extern "C" void kernel_launch(void* const* d_in, const int* in_sizes, int n_in,
                              void* d_out, int out_size, void* d_ws, size_t ws_size,
                              hipStream_t stream)
{
    const float* x       = (const float*)d_in[0];
    const float* w_ih_up = (const float*)d_in[1];
    const float* w_hh_up = (const float*)d_in[2];
    const float* b_ih_up = (const float*)d_in[3];
    const float* b_hh_up = (const float*)d_in[4];
    const float* w1      = (const float*)d_in[5];
    const float* b1      = (const float*)d_in[6];
    const float* w2      = (const float*)d_in[7];
    const float* b2      = (const float*)d_in[8];
    const float* w_ih_dn = (const float*)d_in[9];
    const float* w_hh_dn = (const float*)d_in[10];
    const float* b_ih_dn = (const float*)d_in[11];
    const float* b_hh_dn = (const float*)d_in[12];
    const float* w_out   = (const float*)d_in[13];
    const float* b_out   = (const float*)d_in[14];
    float* out = (float*)d_out;

    const int n = in_sizes[0] / 18;
    const int block = 256;
    const int grid = (n + block - 1) / block;

    trec_kernel<<<grid, block, 0, stream>>>(
        x, w_ih_up, w_hh_up, b_ih_up, b_hh_up,
        w1, b1, w2, b2,
        w_ih_dn, w_hh_dn, b_ih_dn, b_hh_dn,
        w_out, b_out, out, n);
}